// Round 8
// baseline (158.688 us; speedup 1.0000x reference)
//
#include <hip/hip_runtime.h>

// Problem constants (from reference setup_inputs)
#define NB 8
#define LQ 512
#define LC 2048
#define DD 768

typedef _Float16 f16x8 __attribute__((ext_vector_type(8)));
typedef _Float16 f16x4 __attribute__((ext_vector_type(4)));
typedef float    f32x4 __attribute__((ext_vector_type(4)));

__device__ __forceinline__ void dma16(const _Float16* g, char* l) {
    __builtin_amdgcn_global_load_lds(
        (const __attribute__((address_space(1))) unsigned int*)g,
        (__attribute__((address_space(3))) unsigned int*)l,
        16, 0, 0);
}

// ---------------------------------------------------------------------------
// K0: convert Q fp32 -> Qh [b][q][d] fp16  AND  QhT [b][d][q] fp16
// ---------------------------------------------------------------------------
__global__ __launch_bounds__(256) void preconvert_q(const float* __restrict__ Q,
                                                    _Float16* __restrict__ Qh,
                                                    _Float16* __restrict__ QhT) {
    __shared__ _Float16 lt[64][68];
    const int blk = blockIdx.x;
    const int b   = blk / 96;
    const int rem = blk % 96;
    const int q0  = (rem / 12) * 64;
    const int d0  = (rem % 12) * 64;
    const int t   = threadIdx.x;
    const int tr  = t >> 4;
    const int tc  = t & 15;

    const float* Qb  = Q  + ((size_t)b * LQ + q0) * DD + d0;
    _Float16*    Qhb = Qh + ((size_t)b * LQ + q0) * DD + d0;

#pragma unroll
    for (int i = 0; i < 4; i++) {
        const int row = i * 16 + tr;
        const int col = tc * 4;
        f32x4 v = *(const f32x4*)(Qb + (size_t)row * DD + col);
        f16x4 h;
        h.x = (_Float16)v.x; h.y = (_Float16)v.y;
        h.z = (_Float16)v.z; h.w = (_Float16)v.w;
        *(f16x4*)(Qhb + (size_t)row * DD + col) = h;
        *(f16x4*)&lt[row][col] = h;
    }
    __syncthreads();

    _Float16* QTb = QhT + ((size_t)b * DD + d0) * LQ + q0;
#pragma unroll
    for (int i = 0; i < 4; i++) {
        const int drow = i * 16 + tr;
        const int qc   = tc * 4;
        f16x4 h;
        h.x = lt[qc + 0][drow];
        h.y = lt[qc + 1][drow];
        h.z = lt[qc + 2][drow];
        h.w = lt[qc + 3][drow];
        *(f16x4*)(QTb + (size_t)drow * LQ + qc) = h;
    }
}

// ---------------------------------------------------------------------------
// v13: 3-kernel pipeline. R7 diagnosis: the fused 160KB/1-block/CU design has
// ZERO inter-pipe overlap (sum of serial pipe times = 72us = measured), and
// its 96KB full-K A-tile makes deeper pipelining LDS-infeasible. Fix: split
// into two chunk-staged GEMMs with 2-4 blocks/CU so BLOCKS overlap pipes.
//
// Shared swizzle (both kernels, v12b-verified): LDS rows are 64B (4x16B
// slots); LDS slot s of row r holds global 16B-slot s ^ f(r),
// f(r) = (r&3)^((r>>2)&3) -> a 16-lane frag read (rows l15, slot quad)
// spreads over 8 bank groups = 2-way = free. DMA dest stays linear
// (addr = t*16), source address pre-swizzled per lane.
// ---------------------------------------------------------------------------

// ========================= K1: S=ctx@Qh^T + softmax -> P ====================
// Block: 64 c-rows x 512 q (full), K=768 in 24 chunks of 32. 512 thr, 8 waves.
// LDS 76KB -> 2 blocks/CU: Bbuf 2x32KB | Abuf 2x4KB | red 2x2KB.
#define K1_B0   0
#define K1_B1   32768
#define K1_A0   65536
#define K1_A1   69632
#define K1_RMAX 73728
#define K1_RSUM 75776
#define K1_SMEM 77824

__global__ __launch_bounds__(512, 4) void qk_softmax(const float* __restrict__ ctx,
                                                     const _Float16* __restrict__ Qh,
                                                     _Float16* __restrict__ P) {
    __shared__ __align__(16) char smem[K1_SMEM];
    float (*red_max)[64] = (float (*)[64])(smem + K1_RMAX);
    float (*red_sum)[64] = (float (*)[64])(smem + K1_RSUM);

    const int b    = blockIdx.x & 7;          // XCD-affine batch
    const int c0   = (blockIdx.x >> 3) * 64;
    const int t    = threadIdx.x;
    const int w    = t >> 6;
    const int lane = t & 63;
    const int quad = lane >> 4;
    const int l15  = lane & 15;

    const _Float16* QhB = Qh + (size_t)b * LQ * DD;

    // B staging (DMA): thread t covers LDS addr t*16 (row=t>>2, slot=t&3)
    const int srow = t >> 2;                                  // 0..127
    const int sB   = (t & 3) ^ (srow & 3) ^ ((srow >> 2) & 3);
    const _Float16* stB = QhB + (size_t)srow * DD + sB * 8;   // + j*128*DD + kc*32
    char* dmaW = smem + (size_t)w * 1024;

    // A staging (reg, f32->f16): thread t -> row t>>3, slot (t&7)>>1, half t&1
    const int arow = t >> 3;                                  // 0..63
    const int ags  = (t & 7) >> 1;
    const int ah   = t & 1;
    const int asw  = ags ^ (arow & 3) ^ ((arow >> 2) & 3);
    const float* ctxA = ctx + ((size_t)b * LC + c0 + arow) * DD + asw * 8 + ah * 4;
    const int aWoff = arow * 64 + ags * 16 + ah * 8;

    // fragment-read slot offset (lane-constant)
    const int fl   = (l15 & 3) ^ ((l15 >> 2) & 3);
    const int bsub = (quad ^ fl) * 16;

    // prologue: chunk 0 in flight / staged
#pragma unroll
    for (int j = 0; j < 4; j++)
        dma16(stB + (size_t)(j * 128) * DD, dmaW + K1_B0 + j * 8192);
    {
        f32x4 v = *(const f32x4*)ctxA;
        f16x4 h; h.x = (_Float16)v.x; h.y = (_Float16)v.y;
        h.z = (_Float16)v.z; h.w = (_Float16)v.w;
        *(f16x4*)(smem + K1_A0 + aWoff) = h;
    }

    f32x4 acc[4][4];
#pragma unroll
    for (int mt = 0; mt < 4; mt++)
#pragma unroll
        for (int nt = 0; nt < 4; nt++)
            acc[mt][nt] = (f32x4){0.f, 0.f, 0.f, 0.f};

#pragma unroll
    for (int kc = 0; kc < 24; kc++) {
        __syncthreads();   // publish chunk kc (drains its DMA), WAR-safe for kc+1
        f16x4 aS;
        if (kc + 1 < 24) {
            char* nb = dmaW + (((kc + 1) & 1) ? K1_B1 : K1_B0);
            const _Float16* src = stB + (kc + 1) * 32;
#pragma unroll
            for (int j = 0; j < 4; j++)
                dma16(src + (size_t)(j * 128) * DD, nb + j * 8192);
            f32x4 v = *(const f32x4*)(ctxA + (kc + 1) * 32);
            aS.x = (_Float16)v.x; aS.y = (_Float16)v.y;
            aS.z = (_Float16)v.z; aS.w = (_Float16)v.w;
        }
        const char* bbuf = smem + ((kc & 1) ? K1_B1 : K1_B0);
        const char* abuf = smem + ((kc & 1) ? K1_A1 : K1_A0);
        f16x8 a[4], bq[4];
#pragma unroll
        for (int mt = 0; mt < 4; mt++)
            a[mt] = *(const f16x8*)(abuf + (size_t)(mt * 16 + l15) * 64 + bsub);
#pragma unroll
        for (int nt = 0; nt < 4; nt++)
            bq[nt] = *(const f16x8*)(bbuf + (size_t)(w * 64 + nt * 16 + l15) * 64 + bsub);
        if (kc + 1 < 24)
            *(f16x4*)(smem + (((kc + 1) & 1) ? K1_A1 : K1_A0) + aWoff) = aS;
        __builtin_amdgcn_s_setprio(1);
#pragma unroll
        for (int nt = 0; nt < 4; nt++)
#pragma unroll
            for (int mt = 0; mt < 4; mt++)
                acc[mt][nt] = __builtin_amdgcn_mfma_f32_16x16x32_f16(a[mt], bq[nt], acc[mt][nt], 0, 0, 0);
        __builtin_amdgcn_s_setprio(0);
    }

    // ---------------- softmax over q (same layout as fused version) ---------
    float rm[4][4];
#pragma unroll
    for (int mt = 0; mt < 4; mt++)
#pragma unroll
        for (int r = 0; r < 4; r++)
            rm[mt][r] = -1e30f;
#pragma unroll
    for (int mt = 0; mt < 4; mt++)
#pragma unroll
        for (int nt = 0; nt < 4; nt++) {
            rm[mt][0] = fmaxf(rm[mt][0], acc[mt][nt].x);
            rm[mt][1] = fmaxf(rm[mt][1], acc[mt][nt].y);
            rm[mt][2] = fmaxf(rm[mt][2], acc[mt][nt].z);
            rm[mt][3] = fmaxf(rm[mt][3], acc[mt][nt].w);
        }
#pragma unroll
    for (int off = 1; off < 16; off <<= 1)
#pragma unroll
        for (int mt = 0; mt < 4; mt++)
#pragma unroll
            for (int r = 0; r < 4; r++)
                rm[mt][r] = fmaxf(rm[mt][r], __shfl_xor(rm[mt][r], off));
    if (l15 == 0) {
#pragma unroll
        for (int mt = 0; mt < 4; mt++)
#pragma unroll
            for (int r = 0; r < 4; r++)
                red_max[w][mt * 16 + quad * 4 + r] = rm[mt][r];
    }
    __syncthreads();

    float fm[4][4];
#pragma unroll
    for (int mt = 0; mt < 4; mt++)
#pragma unroll
        for (int r = 0; r < 4; r++) {
            const int row = mt * 16 + quad * 4 + r;
            float m0 = fmaxf(fmaxf(red_max[0][row], red_max[1][row]),
                             fmaxf(red_max[2][row], red_max[3][row]));
            float m1 = fmaxf(fmaxf(red_max[4][row], red_max[5][row]),
                             fmaxf(red_max[6][row], red_max[7][row]));
            fm[mt][r] = fmaxf(m0, m1);
        }
    float rs[4][4];
#pragma unroll
    for (int mt = 0; mt < 4; mt++)
#pragma unroll
        for (int r = 0; r < 4; r++)
            rs[mt][r] = 0.f;
#pragma unroll
    for (int mt = 0; mt < 4; mt++)
#pragma unroll
        for (int nt = 0; nt < 4; nt++) {
            float e0 = __expf(acc[mt][nt].x - fm[mt][0]);
            float e1 = __expf(acc[mt][nt].y - fm[mt][1]);
            float e2 = __expf(acc[mt][nt].z - fm[mt][2]);
            float e3 = __expf(acc[mt][nt].w - fm[mt][3]);
            acc[mt][nt].x = e0; acc[mt][nt].y = e1;
            acc[mt][nt].z = e2; acc[mt][nt].w = e3;
            rs[mt][0] += e0; rs[mt][1] += e1; rs[mt][2] += e2; rs[mt][3] += e3;
        }
#pragma unroll
    for (int off = 1; off < 16; off <<= 1)
#pragma unroll
        for (int mt = 0; mt < 4; mt++)
#pragma unroll
            for (int r = 0; r < 4; r++)
                rs[mt][r] += __shfl_xor(rs[mt][r], off);
    if (l15 == 0) {
#pragma unroll
        for (int mt = 0; mt < 4; mt++)
#pragma unroll
            for (int r = 0; r < 4; r++)
                red_sum[w][mt * 16 + quad * 4 + r] = rs[mt][r];
    }
    __syncthreads();

    _Float16* Pb = P + ((size_t)b * LC + c0) * LQ;
#pragma unroll
    for (int mt = 0; mt < 4; mt++)
#pragma unroll
        for (int r = 0; r < 4; r++) {
            const int row = mt * 16 + quad * 4 + r;
            float s = 0.f;
#pragma unroll
            for (int j = 0; j < 8; j++) s += red_sum[j][row];
            const float inv = 1.0f / s;
#pragma unroll
            for (int nt = 0; nt < 4; nt++) {
                const int q = w * 64 + nt * 16 + l15;
                float v = (r == 0 ? acc[mt][nt].x : r == 1 ? acc[mt][nt].y
                          : r == 2 ? acc[mt][nt].z : acc[mt][nt].w);
                Pb[(size_t)row * LQ + q] = (_Float16)(v * inv);
            }
        }
}

// ========================= K2: out = ctx * (P @ Q) ==========================
// Block: 128 c x 128 d, K=512 in 16 chunks of 32. 256 thr, 4 waves (2x2).
// LDS 32KB -> 4 blocks/CU: Abuf 2x8KB | Bbuf 2x8KB. Both operands DMA-staged.
#define K2_A0 0
#define K2_A1 8192
#define K2_B0 16384
#define K2_B1 24576
#define K2_SMEM 32768

__global__ __launch_bounds__(256, 4) void pv_gate(const float* __restrict__ ctx,
                                                  const _Float16* __restrict__ P,
                                                  const _Float16* __restrict__ QhT,
                                                  float* __restrict__ out) {
    __shared__ __align__(16) char smem[K2_SMEM];

    const int b    = blockIdx.x & 7;          // XCD-affine batch
    const int r8   = blockIdx.x >> 3;         // 0..95
    const int c0   = (r8 % 16) * 128;
    const int d0   = (r8 / 16) * 128;
    const int t    = threadIdx.x;
    const int w    = t >> 6;                  // wave 0..3
    const int lane = t & 63;
    const int quad = lane >> 4;
    const int l15  = lane & 15;
    const int wr   = w >> 1;                  // wave row (c) 0..1
    const int wc   = w & 1;                   // wave col (d) 0..1

    // staging: DMA call j covers rows j*64 + (t>>2), slot t&3 -> addr j*4096 + t*16
    const int srow = t >> 2;                  // 0..63
    const int sS   = (t & 3) ^ (srow & 3) ^ ((srow >> 2) & 3);
    const _Float16* stA = P   + ((size_t)b * LC + c0 + srow) * LQ + sS * 8;
    const _Float16* stB = QhT + ((size_t)b * DD + d0 + srow) * LQ + sS * 8;
    char* dmaW = smem + (size_t)w * 1024;

    const int fl   = (l15 & 3) ^ ((l15 >> 2) & 3);
    const int bsub = (quad ^ fl) * 16;

    // prologue: chunk 0 DMA
#pragma unroll
    for (int j = 0; j < 2; j++) {
        dma16(stA + (size_t)(j * 64) * LQ, dmaW + K2_A0 + j * 4096);
        dma16(stB + (size_t)(j * 64) * LQ, dmaW + K2_B0 + j * 4096);
    }

    f32x4 acc[4][4];
#pragma unroll
    for (int mt = 0; mt < 4; mt++)
#pragma unroll
        for (int nt = 0; nt < 4; nt++)
            acc[mt][nt] = (f32x4){0.f, 0.f, 0.f, 0.f};

#pragma unroll
    for (int kc = 0; kc < 16; kc++) {
        __syncthreads();   // publish chunk kc (drains its DMA)
        if (kc + 1 < 16) {
            const int nb = ((kc + 1) & 1);
            const _Float16* sa = stA + (kc + 1) * 32;
            const _Float16* sb = stB + (kc + 1) * 32;
#pragma unroll
            for (int j = 0; j < 2; j++) {
                dma16(sa + (size_t)(j * 64) * LQ, dmaW + (nb ? K2_A1 : K2_A0) + j * 4096);
                dma16(sb + (size_t)(j * 64) * LQ, dmaW + (nb ? K2_B1 : K2_B0) + j * 4096);
            }
        }
        const char* abuf = smem + ((kc & 1) ? K2_A1 : K2_A0);
        const char* bbuf = smem + ((kc & 1) ? K2_B1 : K2_B0);
        f16x8 a[4], bq[4];
#pragma unroll
        for (int mt = 0; mt < 4; mt++)
            a[mt] = *(const f16x8*)(abuf + (size_t)(wr * 64 + mt * 16 + l15) * 64 + bsub);
#pragma unroll
        for (int nt = 0; nt < 4; nt++)
            bq[nt] = *(const f16x8*)(bbuf + (size_t)(wc * 64 + nt * 16 + l15) * 64 + bsub);
        __builtin_amdgcn_s_setprio(1);
#pragma unroll
        for (int nt = 0; nt < 4; nt++)
#pragma unroll
            for (int mt = 0; mt < 4; mt++)
                acc[mt][nt] = __builtin_amdgcn_mfma_f32_16x16x32_f16(a[mt], bq[nt], acc[mt][nt], 0, 0, 0);
        __builtin_amdgcn_s_setprio(0);
    }

    // epilogue: out = ctx * awq
#pragma unroll
    for (int mt = 0; mt < 4; mt++)
#pragma unroll
        for (int nt = 0; nt < 4; nt++) {
            const int col = d0 + wc * 64 + nt * 16 + l15;
#pragma unroll
            for (int r = 0; r < 4; r++) {
                const int row = c0 + wr * 64 + mt * 16 + quad * 4 + r;
                const size_t idx = ((size_t)b * LC + row) * DD + col;
                float v = (r == 0 ? acc[mt][nt].x : r == 1 ? acc[mt][nt].y
                          : r == 2 ? acc[mt][nt].z : acc[mt][nt].w);
                out[idx] = ctx[idx] * v;
            }
        }
}

extern "C" void kernel_launch(void* const* d_in, const int* in_sizes, int n_in,
                              void* d_out, int out_size, void* d_ws, size_t ws_size,
                              hipStream_t stream) {
    const float* ctx = (const float*)d_in[0];   // [8][2048][768] f32
    const float* q   = (const float*)d_in[1];   // [8][512][768]  f32
    float* out = (float*)d_out;

    const size_t nQ = (size_t)NB * LQ * DD;     // 3,145,728
    _Float16* Qh  = (_Float16*)d_ws;
    _Float16* QhT = Qh + nQ;
    _Float16* Pws = QhT + nQ;                   // [8][2048][512] f16, 16.8 MB
                                                // total ws use 29.4 MB (R0 proved >=37.7 available)

    preconvert_q<<<dim3(NB * 96), dim3(256), 0, stream>>>(q, Qh, QhT);
    qk_softmax<<<dim3(NB * (LC / 64)), dim3(512), 0, stream>>>(ctx, Qh, Pws);
    pv_gate<<<dim3(NB * (LC / 128) * (DD / 128)), dim3(256), 0, stream>>>(ctx, Pws, QhT, out);
}